// Round 7
// baseline (1472.553 us; speedup 1.0000x reference)
//
#include <hip/hip_runtime.h>
#include <hip/hip_bf16.h>

// RGAT pipeline for MI355X. Inputs f32, OUTPUTS f32 (round-6 analysis: the
// 1.80078125 error decomposes exactly as a bf16-halfword misread of an f32
// buffer; harness reads d_out as f32, bf16 appears only in its ref-rounding).
// Scratch (81.4 MB) lives in d_out's f32 adj region (144 MB), all dead before
// adj_kernel, which reads mu from out_mu (disjoint from the adj range it
// writes). d_ws and d_in are untouched.

static constexpr int N_  = 20000;
static constexpr int R_  = 3;
static constexpr int E_  = 200000;
static constexpr int NB1 = 6000;   // N1 == N2 == 6000

__device__ __forceinline__ float sigmoidf_(float x) {
  return 1.0f / (1.0f + __expf(-x));
}

// ---------------- CSR build ----------------
__global__ void hist_kernel(const int* __restrict__ dst, int* __restrict__ counts) {
  int i = blockIdx.x * blockDim.x + threadIdx.x;
  if (i >= R_ * E_) return;
  int r = i / E_;
  atomicAdd(&counts[r * N_ + dst[i]], 1);
}

__global__ void scan_kernel(const int* __restrict__ counts, int* __restrict__ ptr) {
  int r = blockIdx.x;
  __shared__ int buf[1024];
  __shared__ int carry;
  int tid = threadIdx.x;
  if (tid == 0) carry = 0;
  __syncthreads();
  for (int base = 0; base < N_; base += 1024) {
    int i = base + tid;
    int v = (i < N_) ? counts[r * N_ + i] : 0;
    buf[tid] = v;
    __syncthreads();
    for (int off = 1; off < 1024; off <<= 1) {
      int t = (tid >= off) ? buf[tid - off] : 0;
      __syncthreads();
      buf[tid] += t;
      __syncthreads();
    }
    int c = carry;
    if (i < N_) ptr[r * (N_ + 1) + i] = c + buf[tid] - v;  // exclusive scan
    __syncthreads();
    if (tid == 1023) carry = c + buf[1023];
    __syncthreads();
  }
  if (tid == 0) ptr[r * (N_ + 1) + N_] = carry;
}

__global__ void scatter_kernel(const int* __restrict__ src, const int* __restrict__ dst,
                               const int* __restrict__ ptr, int* __restrict__ fill,
                               int* __restrict__ csrc) {
  int i = blockIdx.x * blockDim.x + threadIdx.x;
  if (i >= R_ * E_) return;
  int r = i / E_;
  int d = dst[i];
  int pos = ptr[r * (N_ + 1) + d] + atomicAdd(&fill[r * N_ + d], 1);
  csrc[r * E_ + pos] = src[i];
}

// ---------------- GEMM + fused attention-logit epilogue ----------------
// h[r][n][HF] = A[n][:] @ W[r][:][:] (f32); el/er[r][n][hh] = sum_f h*al/ar.
// 256 threads = 16x16, tile 64 nodes x 64 cols, 4x4 register blocking.
template <int DIN, int HF, int H, int F>
__global__ __launch_bounds__(256) void gemm_el_kernel(
    const float* __restrict__ A, const float* __restrict__ W,
    const float* __restrict__ al, const float* __restrict__ ar,
    float* __restrict__ h, float* __restrict__ el, float* __restrict__ er) {
  __shared__ float sAT[64][68];  // [k][node]
  __shared__ float sW[64][68];   // [k][col]
  const int nb  = blockIdx.x * 64;
  const int cg  = blockIdx.y;    // 64-col group
  const int r   = blockIdx.z;
  const int tid = threadIdx.x;
  const int ty  = tid >> 4, tx = tid & 15;

  float acc[4][4];
#pragma unroll
  for (int i = 0; i < 4; ++i)
#pragma unroll
    for (int j = 0; j < 4; ++j) acc[i][j] = 0.f;

  for (int k0 = 0; k0 < DIN; k0 += 64) {
    for (int idx = tid; idx < 4096; idx += 256) {
      int nl = idx >> 6, kk = idx & 63;
      int n = nb + nl;
      sAT[kk][nl] = (n < N_) ? A[(size_t)n * DIN + k0 + kk] : 0.f;
    }
    for (int idx = tid; idx < 4096; idx += 256) {
      int kk = idx >> 6, cl = idx & 63;
      sW[kk][cl] = W[((size_t)r * DIN + k0 + kk) * HF + cg * 64 + cl];
    }
    __syncthreads();
#pragma unroll 8
    for (int kk = 0; kk < 64; ++kk) {
      const float4 a4 = *(const float4*)&sAT[kk][ty * 4];
      const float4 w4 = *(const float4*)&sW[kk][tx * 4];
      const float a[4] = {a4.x, a4.y, a4.z, a4.w};
      const float w[4] = {w4.x, w4.y, w4.z, w4.w};
#pragma unroll
      for (int i = 0; i < 4; ++i)
#pragma unroll
        for (int j = 0; j < 4; ++j) acc[i][j] = fmaf(a[i], w[j], acc[i][j]);
    }
    __syncthreads();
  }

  // store h (float4 per row)
  const int c0 = cg * 64 + tx * 4;
#pragma unroll
  for (int i = 0; i < 4; ++i) {
    int n = nb + ty * 4 + i;
    if (n < N_) {
      float4 v; v.x = acc[i][0]; v.y = acc[i][1]; v.z = acc[i][2]; v.w = acc[i][3];
      *(float4*)&h[((size_t)r * N_ + n) * HF + c0] = v;
    }
  }

  // fused el/er: reduce over f within head via shuffles (group width G = F/4)
  const int hh = c0 / F;
  const int f0 = c0 % F;
  float al4[4], ar4[4];
#pragma unroll
  for (int j = 0; j < 4; ++j) {
    al4[j] = al[((size_t)r * H + hh) * F + f0 + j];
    ar4[j] = ar[((size_t)r * H + hh) * F + f0 + j];
  }
  float elp[4], erp[4];
#pragma unroll
  for (int i = 0; i < 4; ++i) {
    elp[i] = acc[i][0] * al4[0] + acc[i][1] * al4[1] + acc[i][2] * al4[2] + acc[i][3] * al4[3];
    erp[i] = acc[i][0] * ar4[0] + acc[i][1] * ar4[1] + acc[i][2] * ar4[2] + acc[i][3] * ar4[3];
  }
  constexpr int G = F / 4;  // tx-threads per head: 16 (F=64) or 8 (F=32)
#pragma unroll
  for (int off = G / 2; off >= 1; off >>= 1) {
#pragma unroll
    for (int i = 0; i < 4; ++i) {
      elp[i] += __shfl_down(elp[i], off, G);
      erp[i] += __shfl_down(erp[i], off, G);
    }
  }
  if ((tx & (G - 1)) == 0) {
#pragma unroll
    for (int i = 0; i < 4; ++i) {
      int n = nb + ty * 4 + i;
      if (n < N_) {
        el[((size_t)r * N_ + n) * H + hh] = elp[i];
        er[((size_t)r * N_ + n) * H + hh] = erp[i];
      }
    }
  }
}

// ---------------- Per-destination edge softmax + aggregation ----------------
// One block per node; wave = head. Accumulate over R relations (f32), then
// head-mean + activation + optional f32 base add; write f32.
template <int H, int F, bool RELU>
__global__ __launch_bounds__(256) void agg_kernel(
    const float* __restrict__ h, const float* __restrict__ el, const float* __restrict__ er,
    const int* __restrict__ ptr, const int* __restrict__ srcs,
    const float* __restrict__ base, float* __restrict__ outf) {
  const int n = blockIdx.x;
  const int wave = threadIdx.x >> 6;
  const int lane = threadIdx.x & 63;
  float acc = 0.f;

  for (int r = 0; r < R_; ++r) {
    const int p0 = ptr[r * (N_ + 1) + n];
    const int deg = ptr[r * (N_ + 1) + n + 1] - p0;
    if (deg == 0) continue;
    const int* sp = srcs + (size_t)r * E_ + p0;
    const float erv = er[((size_t)r * N_ + n) * H + wave];

    // phase 1: segment max
    float m = -3.0e38f;
    for (int i = lane; i < deg; i += 64) {
      int s = sp[i];
      float e = el[((size_t)r * N_ + s) * H + wave] + erv;
      e = (e > 0.f) ? e : 0.2f * e;
      m = fmaxf(m, e);
    }
#pragma unroll
    for (int off = 32; off >= 1; off >>= 1) m = fmaxf(m, __shfl_xor(m, off, 64));

    // phase 2: denom
    float dsum = 0.f;
    for (int i = lane; i < deg; i += 64) {
      int s = sp[i];
      float e = el[((size_t)r * N_ + s) * H + wave] + erv;
      e = (e > 0.f) ? e : 0.2f * e;
      dsum += __expf(e - m);
    }
#pragma unroll
    for (int off = 32; off >= 1; off >>= 1) dsum += __shfl_xor(dsum, off, 64);
    const float inv = 1.0f / (dsum + 1e-16f);

    // phase 3: weighted gather of h rows
    for (int i = 0; i < deg; ++i) {
      int s = sp[i];
      float e = el[((size_t)r * N_ + s) * H + wave] + erv;
      e = (e > 0.f) ? e : 0.2f * e;
      float a = __expf(e - m) * inv;
      if (lane < F)
        acc = fmaf(a, h[((size_t)r * N_ + s) * (H * F) + wave * F + lane], acc);
    }
  }

  __shared__ float sh[H][F];
  if (lane < F) sh[wave][lane] = acc;
  __syncthreads();
  if (wave == 0 && lane < F) {
    float v = 0.f;
#pragma unroll
    for (int hh = 0; hh < H; ++hh) v += sh[hh][lane];
    v *= (1.0f / H);
    if (RELU) v = fmaxf(v, 0.f);
    if (base) v += base[(size_t)n * F + lane];
    outf[(size_t)n * F + lane] = v;
  }
}

// ---------------- adj = mean_s sigmoid(z1[s] @ z2[s]^T) ----------------
// Reads f32 mu from out_mu (d_out elements [36M,37.28M)) and writes only the
// adj range [0,36M) -- disjoint, no hazard. 256 threads = 16x16, tile 128x128,
// 8x8 register blocking, s staged via LDS.
__global__ __launch_bounds__(256) void adj_kernel(const float* __restrict__ mu,
                                                  float* __restrict__ out) {
  __shared__ float sA[32][132];  // [d][i_local]
  __shared__ float sB[32][132];  // [d][j_local]
  const int jb = blockIdx.x * 128;
  const int ib = blockIdx.y * 128;
  const int tid = threadIdx.x;
  const int ty = tid >> 4, tx = tid & 15;

  float res[8][8];
#pragma unroll
  for (int i = 0; i < 8; ++i)
#pragma unroll
    for (int j = 0; j < 8; ++j) res[i][j] = 0.f;

  for (int s = 0; s < 2; ++s) {
    __syncthreads();
    for (int idx = tid; idx < 128 * 32; idx += 256) {
      int d = idx & 31, row = idx >> 5;
      int gi = ib + row;
      int gj = jb + row;
      sA[d][row] = (gi < NB1) ? mu[((size_t)s * N_ + gi) * 32 + d] : 0.f;
      sB[d][row] = (gj < NB1) ? mu[((size_t)s * N_ + NB1 + gj) * 32 + d] : 0.f;
    }
    __syncthreads();
    float acc[8][8];
#pragma unroll
    for (int i = 0; i < 8; ++i)
#pragma unroll
      for (int j = 0; j < 8; ++j) acc[i][j] = 0.f;
#pragma unroll 4
    for (int k = 0; k < 32; ++k) {
      float a[8], b[8];
      *(float4*)&a[0] = *(const float4*)&sA[k][ty * 8];
      *(float4*)&a[4] = *(const float4*)&sA[k][ty * 8 + 4];
      *(float4*)&b[0] = *(const float4*)&sB[k][tx * 8];
      *(float4*)&b[4] = *(const float4*)&sB[k][tx * 8 + 4];
#pragma unroll
      for (int i = 0; i < 8; ++i)
#pragma unroll
        for (int j = 0; j < 8; ++j) acc[i][j] = fmaf(a[i], b[j], acc[i][j]);
    }
#pragma unroll
    for (int i = 0; i < 8; ++i)
#pragma unroll
      for (int j = 0; j < 8; ++j) res[i][j] += sigmoidf_(acc[i][j]);
  }

  const bool fullc = (jb + 128) <= NB1;
#pragma unroll
  for (int i = 0; i < 8; ++i) {
    int row = ib + ty * 8 + i;
    if (row < NB1) {
      if (fullc) {
        float4 p0, p1;
        p0.x = 0.5f * res[i][0]; p0.y = 0.5f * res[i][1];
        p0.z = 0.5f * res[i][2]; p0.w = 0.5f * res[i][3];
        p1.x = 0.5f * res[i][4]; p1.y = 0.5f * res[i][5];
        p1.z = 0.5f * res[i][6]; p1.w = 0.5f * res[i][7];
        *(float4*)&out[(size_t)row * NB1 + jb + tx * 8]     = p0;
        *(float4*)&out[(size_t)row * NB1 + jb + tx * 8 + 4] = p1;
      } else {
#pragma unroll
        for (int j = 0; j < 8; ++j) {
          int col = jb + tx * 8 + j;
          if (col < NB1) out[(size_t)row * NB1 + col] = 0.5f * res[i][j];
        }
      }
    }
  }
}

__global__ void rk2_kernel(const float* __restrict__ rk_lgt, float* __restrict__ out) {
  int i = threadIdx.x;
  if (i < 32) out[i] = sigmoidf_(rk_lgt[i]);
}

// ---------------- host ----------------
static inline size_t align256(size_t x) { return (x + 255) & ~(size_t)255; }

extern "C" void kernel_launch(void* const* d_in, const int* in_sizes, int n_in,
                              void* d_out, int out_size, void* d_ws, size_t ws_size,
                              hipStream_t stream) {
  (void)in_sizes; (void)n_in; (void)out_size; (void)d_ws; (void)ws_size;
  const float* x      = (const float*)d_in[0];
  const float* noise  = (const float*)d_in[1];
  const float* W1     = (const float*)d_in[2];
  const float* al1    = (const float*)d_in[3];
  const float* ar1    = (const float*)d_in[4];
  const float* We     = (const float*)d_in[5];
  const float* ale    = (const float*)d_in[6];
  const float* are    = (const float*)d_in[7];
  const float* W2     = (const float*)d_in[8];
  const float* al2    = (const float*)d_in[9];
  const float* ar2    = (const float*)d_in[10];
  const float* W3     = (const float*)d_in[11];
  const float* al3    = (const float*)d_in[12];
  const float* ar3    = (const float*)d_in[13];
  const float* rk_lgt = (const float*)d_in[14];
  const int*   src    = (const int*)d_in[15];
  const int*   dst    = (const int*)d_in[16];

  float* out_adj    = (float*)d_out;                       // (1,6000,6000)
  float* out_mu     = out_adj + (size_t)NB1 * NB1;         // (2,20000,32) @ 36,000,000
  float* out_logvar = out_mu + (size_t)2 * N_ * 32;        // (20000,32)   @ 37,280,000
  float* out_rk2    = out_logvar + (size_t)N_ * 32;        // (1,32)       @ 37,920,000

  // Scratch in the f32 adj region (144 MB; we use 81.4 MB), dead before adj.
  char* sc = (char*)d_out;
  size_t off = 0;
  int*   ptr     = (int*)(sc + off);   off += align256((size_t)R_ * (N_ + 1) * 4);  //    240,128
  int*   csr_src = (int*)(sc + off);   off += align256((size_t)R_ * E_ * 4);        //  2,400,256
  float* el      = (float*)(sc + off); off += align256((size_t)R_ * N_ * 4 * 4);    //    960,000
  float* er      = (float*)(sc + off); off += align256((size_t)R_ * N_ * 4 * 4);    //    960,000
  float* hx      = (float*)(sc + off); off += align256((size_t)N_ * 64 * 4);        //  5,120,000
  float* h1      = (float*)(sc + off); off += align256((size_t)2 * N_ * 64 * 4);    // 10,240,000
  float* h       = (float*)(sc + off); off += align256((size_t)R_ * N_ * 256 * 4);  // 61,440,000
  // total 81,360,384 B < 144,000,000 B (f32 adj region)
  // counts/fill alias the h region (dead after CSR build; h written later)
  int* counts = (int*)(void*)h;
  int* fill   = (int*)(void*)((char*)(void*)h + align256((size_t)R_ * N_ * 4));

  // ---- CSR (dst shared by all 6 rgat calls) ----
  hipMemsetAsync(counts, 0, (size_t)R_ * N_ * 4, stream);
  hipMemsetAsync(fill, 0, (size_t)R_ * N_ * 4, stream);
  int eblocks = (R_ * E_ + 255) / 256;
  hist_kernel<<<eblocks, 256, 0, stream>>>(dst, counts);
  scan_kernel<<<R_, 1024, 0, stream>>>(counts, ptr);
  scatter_kernel<<<eblocks, 256, 0, stream>>>(src, dst, ptr, fill, csr_src);

  const dim3 g256((N_ + 63) / 64, 4, R_);
  const dim3 g64((N_ + 63) / 64, 1, R_);

  // hiddenx = rgat(x, W1, al1, ar1, relu) -> hx (f32)
  gemm_el_kernel<128, 256, 4, 64><<<g256, 256, 0, stream>>>(x, W1, al1, ar1, h, el, er);
  agg_kernel<4, 64, true><<<N_, 256, 0, stream>>>(h, el, er, ptr, csr_src, nullptr, hx);

  // hidden1[s] = hiddenx + rgat(noise[s], We, ale, are, relu) -> h1 (f32)
  for (int s = 0; s < 2; ++s) {
    gemm_el_kernel<64, 256, 4, 64><<<g256, 256, 0, stream>>>(
        noise + (size_t)s * N_ * 64, We, ale, are, h, el, er);
    agg_kernel<4, 64, true><<<N_, 256, 0, stream>>>(
        h, el, er, ptr, csr_src, hx, h1 + (size_t)s * N_ * 64);
  }

  // mu[s] = rgat(hidden1[s], W2, al2, ar2, ident) -> out_mu (f32, real output)
  for (int s = 0; s < 2; ++s) {
    gemm_el_kernel<64, 64, 2, 32><<<g64, 256, 0, stream>>>(
        h1 + (size_t)s * N_ * 64, W2, al2, ar2, h, el, er);
    agg_kernel<2, 32, false><<<N_, 128, 0, stream>>>(
        h, el, er, ptr, csr_src, nullptr, out_mu + (size_t)s * N_ * 32);
  }

  // logvar = rgat(hiddenx, W3, al3, ar3, ident) -> out_logvar (f32)
  gemm_el_kernel<64, 64, 2, 32><<<g64, 256, 0, stream>>>(hx, W3, al3, ar3, h, el, er);
  agg_kernel<2, 32, false><<<N_, 128, 0, stream>>>(
      h, el, er, ptr, csr_src, nullptr, out_logvar);

  rk2_kernel<<<1, 32, 0, stream>>>(rk_lgt, out_rk2);

  // adj: reads out_mu (disjoint range), overwrites the adj-region scratch.
  adj_kernel<<<dim3((NB1 + 127) / 128, (NB1 + 127) / 128), 256, 0, stream>>>(out_mu, out_adj);
}